// Round 1
// baseline (603.024 us; speedup 1.0000x reference)
//
#include <hip/hip_runtime.h>
#include <hip/hip_bf16.h>

#define DEVI __device__ __forceinline__

typedef __attribute__((ext_vector_type(8))) short abf8;   // 8 x bf16 (4 VGPR)
typedef __attribute__((ext_vector_type(4))) float f32x4;  // MFMA acc

DEVI unsigned short f2bf(float f) {
  union { __hip_bfloat16 h; unsigned short u; } cvt;
  cvt.h = __float2bfloat16(f);
  return cvt.u;
}
DEVI float bf2f(unsigned short u) {
  return __uint_as_float(((unsigned)u) << 16);
}
DEVI void async16(const void* g, void* l) {
  // async global->LDS, 16B per lane; LDS dest = wave-uniform base + lane*16
  __builtin_amdgcn_global_load_lds((__attribute__((address_space(1))) void*)(g),
                                   (__attribute__((address_space(3))) void*)(l), 16, 0, 0);
}

// ---------------- K0: weight prep (bf16 casts + cv_w reorder) ----------------
__global__ __launch_bounds__(256) void k0_prep(const float* __restrict__ pw_w,
                                               const float* __restrict__ cv_w,
                                               unsigned short* __restrict__ pwb,
                                               unsigned short* __restrict__ cvb) {
  int id = blockIdx.x * 256 + threadIdx.x;
  if (id < 65536) pwb[id] = f2bf(pw_w[id]);
  if (id < 589824) {
    int dd = id >> 16;          // dy*3+dx
    int rem = id & 65535;       // oc*256+ic
    cvb[id] = f2bf(cv_w[(size_t)rem * 9 + dd]);
  }
}

// ---------------- K1a: Haar DWT + transpose -> t0[b][4c+k][u][v] bf16 --------
// t0[b,4c+k,u,v] = s_k[b,c,v,u], s from x 2x2 block at (h=2v+r, w=2u+s)
__global__ __launch_bounds__(256) void k1a_dwt(const float* __restrict__ x,
                                               unsigned short* __restrict__ t0) {
  __shared__ __align__(16) float L[64 * 65];   // stride 65: conflict-free phase2
  const int t = threadIdx.x;
  const int u0 = (blockIdx.x & 3) * 32;
  const int v0 = (blockIdx.x >> 2) * 32;
  const int c = blockIdx.y, b = blockIdx.z;
  const float* xp = x + (((size_t)(b * 64 + c)) << 16);
  {
    const int row = t >> 2;  // 0..63 -> h = 2*v0+row
    const float* xr = xp + (size_t)(2 * v0 + row) * 256 + 2 * u0;
    float* Lr = L + row * 65;
    for (int j = 0; j < 4; ++j) {
      int col = ((t & 3) + j * 4) * 4;
      float4 val = *(const float4*)(xr + col);
      Lr[col] = val.x; Lr[col + 1] = val.y; Lr[col + 2] = val.z; Lr[col + 3] = val.w;
    }
  }
  __syncthreads();
  const int vv = t & 31;
  const int us = t >> 5;
  const size_t outc = ((size_t)(b * 256 + c * 4)) << 14;
  for (int pass = 0; pass < 4; ++pass) {
    int uu = us * 4 + pass;
    const float* Lp = L + (2 * vv) * 65 + 2 * uu;
    float a = Lp[0], bb = Lp[1], cc = Lp[65], dd = Lp[66];
    float sll = (a + bb + cc + dd) * 0.5f;
    float sch = (a + bb - cc - dd) * 0.5f;
    float scv = (a - bb + cc - dd) * 0.5f;
    float scd = (a - bb - cc + dd) * 0.5f;
    size_t base = outc + ((u0 + uu) << 7) + (v0 + vv);
    t0[base]         = f2bf(sll);
    t0[base + 16384] = f2bf(sch);
    t0[base + 32768] = f2bf(scv);
    t0[base + 49152] = f2bf(scd);
  }
}

// ---------------- K1b: depthwise 3x3 + bias -> t1 NHWC bf16 [b][u*128+v][ic] -
__global__ __launch_bounds__(256) void k1b_dw(const unsigned short* __restrict__ t0,
                                              const float* __restrict__ dww,
                                              const float* __restrict__ dwb,
                                              unsigned short* __restrict__ t1) {
  __shared__ __align__(16) unsigned short S[32 * 181];  // [ic][10u'][18v'], ic-stride 181
  __shared__ __align__(16) unsigned short O[128 * 32];  // out stage [p][ic32]
  const int t = threadIdx.x;
  const int u0 = (blockIdx.x >> 3) * 8;
  const int v0 = (blockIdx.x & 7) * 16;
  const int icB = blockIdx.y * 32;
  const int b = blockIdx.z;
  const unsigned short* t0b = t0 + (((size_t)(b * 256 + icB)) << 14);
  for (int idx = t; idx < 5760; idx += 256) {
    int ic = idx / 180;
    int r = idx - ic * 180;
    int uu = r / 18;
    int vvq = r - uu * 18;
    int gu = u0 + uu - 1, gv = v0 + vvq - 1;
    unsigned short val = 0;
    if ((unsigned)gu < 128u && (unsigned)gv < 128u)
      val = t0b[((size_t)ic << 14) + (gu << 7) + gv];
    S[ic * 181 + r] = val;
  }
  __syncthreads();
  const int icp = t & 15, uu = (t >> 4) & 7, vh = t >> 7;
  const int cc0 = icB + icp * 2;
  float w0[9], w1[9];
  const float* wp = dww + cc0 * 9;
  for (int i = 0; i < 9; ++i) { w0[i] = wp[i]; w1[i] = wp[9 + i]; }
  const float b0 = dwb[cc0], b1 = dwb[cc0 + 1];
  const unsigned short* S0 = S + (icp * 2) * 181 + uu * 18 + vh * 8;
  const unsigned short* S1 = S0 + 181;
  float a0[3][3], a1[3][3];
  for (int du = 0; du < 3; ++du)
    for (int dv = 0; dv < 2; ++dv) {
      a0[du][dv] = bf2f(S0[du * 18 + dv]);
      a1[du][dv] = bf2f(S1[du * 18 + dv]);
    }
  unsigned* O32 = (unsigned*)O;
  for (int vv = 0; vv < 8; ++vv) {
    for (int du = 0; du < 3; ++du) {
      a0[du][2] = bf2f(S0[du * 18 + vv + 2]);
      a1[du][2] = bf2f(S1[du * 18 + vv + 2]);
    }
    float s0 = b0, s1 = b1;
    for (int du = 0; du < 3; ++du)
      for (int dv = 0; dv < 3; ++dv) {
        s0 += w0[du * 3 + dv] * a0[du][dv];
        s1 += w1[du * 3 + dv] * a1[du][dv];
      }
    int p = uu * 16 + vh * 8 + vv;
    O32[p * 16 + icp] = (unsigned)f2bf(s0) | ((unsigned)f2bf(s1) << 16);
    for (int du = 0; du < 3; ++du) {
      a0[du][0] = a0[du][1]; a0[du][1] = a0[du][2];
      a1[du][0] = a1[du][1]; a1[du][1] = a1[du][2];
    }
  }
  __syncthreads();
  const int p = t >> 1, hf = t & 1;
  const int pu = p >> 4, pv = p & 15;
  size_t gp = (size_t)((u0 + pu) * 128 + (v0 + pv));
  const uint4* src = (const uint4*)(O + p * 32 + hf * 16);
  uint4* dst = (uint4*)(t1 + ((((size_t)b * 16384) + gp) << 8) + icB + hf * 16);
  dst[0] = src[0];
  dst[1] = src[1];
}

// ---------------- K2: pointwise GEMM (M=128oc x N=128p, K=256) + bias --------
// D rows=oc, cols=pixel. Epilogue stages [p][oc] in LDS for coalesced NHWC out.
__global__ __launch_bounds__(256) void k2_pw(const unsigned short* __restrict__ t1,
                                             const unsigned short* __restrict__ pwb,
                                             const float* __restrict__ pw_bias,
                                             unsigned short* __restrict__ t2) {
  __shared__ __align__(16) char smem[34816];
  unsigned short* As = (unsigned short*)smem;            // [128 oc][32 ic]
  unsigned short* Bs = (unsigned short*)(smem + 8192);   // [128 p][32 ic]
  unsigned short* Ost = (unsigned short*)smem;           // [128 p][136] (union)
  const int t = threadIdx.x;
  const int wv = t >> 6, ln = t & 63;
  const int p0 = blockIdx.x * 128;
  const int oc0 = blockIdx.y * 128;
  const int b = blockIdx.z;
  const unsigned short* t1b = t1 + ((size_t)b << 22);
  const int lrow = ln >> 2, lic = (ln & 3) << 3;
  const int q = ln >> 4, cl = ln & 15;
  f32x4 acc[2][8] = {};
  for (int ic0 = 0; ic0 < 256; ic0 += 32) {
    __syncthreads();
    for (int cpy = 0; cpy < 2; ++cpy) {
      int row = wv * 32 + cpy * 16 + lrow;
      async16(pwb + (((size_t)(oc0 + row)) << 8) + ic0 + lic,
              As + (wv * 32 + cpy * 16) * 32);
      async16(t1b + (((size_t)(p0 + row)) << 8) + ic0 + lic,
              Bs + (wv * 32 + cpy * 16) * 32);
    }
    __syncthreads();
    abf8 a0 = *(const abf8*)(As + (wv * 32 + cl) * 32 + q * 8);
    abf8 a1 = *(const abf8*)(As + (wv * 32 + 16 + cl) * 32 + q * 8);
    for (int nt = 0; nt < 8; ++nt) {
      abf8 bf = *(const abf8*)(Bs + (nt * 16 + cl) * 32 + q * 8);
      acc[0][nt] = __builtin_amdgcn_mfma_f32_16x16x32_bf16(a0, bf, acc[0][nt], 0, 0, 0);
      acc[1][nt] = __builtin_amdgcn_mfma_f32_16x16x32_bf16(a1, bf, acc[1][nt], 0, 0, 0);
    }
  }
  __syncthreads();
  for (int mt = 0; mt < 2; ++mt) {
    int ocr = wv * 32 + mt * 16 + q * 4;
    float bb0 = pw_bias[oc0 + ocr],     bb1 = pw_bias[oc0 + ocr + 1];
    float bb2 = pw_bias[oc0 + ocr + 2], bb3 = pw_bias[oc0 + ocr + 3];
    for (int nt = 0; nt < 8; ++nt) {
      int p = nt * 16 + cl;
      short4 pk;
      pk.x = (short)f2bf(acc[mt][nt][0] + bb0);
      pk.y = (short)f2bf(acc[mt][nt][1] + bb1);
      pk.z = (short)f2bf(acc[mt][nt][2] + bb2);
      pk.w = (short)f2bf(acc[mt][nt][3] + bb3);
      *(short4*)(Ost + p * 136 + ocr) = pk;
    }
  }
  __syncthreads();
  const int pr = t >> 1, hf = t & 1;
  const uint4* src = (const uint4*)(Ost + pr * 136 + hf * 64);
  uint4* dst = (uint4*)(t2 + (((size_t)(b * 16384 + p0 + pr)) << 8) + oc0 + hf * 64);
  for (int j = 0; j < 8; ++j) dst[j] = src[j];
}

// ---------------- K3: 3x3 conv implicit GEMM (9 x K=256) + bias + GELU -------
// Block: M=128 oc x N=128 v (one u-row). OOB rows redirect to zero page.
__global__ __launch_bounds__(256) void k3_cv(const unsigned short* __restrict__ t2,
                                             const unsigned short* __restrict__ cvb,
                                             const float* __restrict__ cv_bias,
                                             const unsigned short* __restrict__ zp,
                                             unsigned short* __restrict__ t3) {
  __shared__ __align__(16) char smem[34816];
  unsigned short* As = (unsigned short*)smem;            // [128 oc][32 ic]
  unsigned short* Bs = (unsigned short*)(smem + 8192);   // [128 v][32 ic]
  unsigned short* Ost = (unsigned short*)smem;           // [128 oc][136] (union)
  const int t = threadIdx.x;
  const int wv = t >> 6, ln = t & 63;
  const int oc0 = blockIdx.x * 128;
  const int u = blockIdx.y;
  const int b = blockIdx.z;
  const unsigned short* t2b = t2 + ((size_t)b << 22);
  const int lrow = ln >> 2, lic = (ln & 3) << 3;
  const int q = ln >> 4, cl = ln & 15;
  f32x4 acc[2][8] = {};
  for (int dd = 0; dd < 9; ++dd) {
    const int du = dd / 3, dv = dd - 3 * du;
    const int us = u + du - 1;
    const bool uok = (unsigned)us < 128u;
    const unsigned short* wbase = cvb + ((size_t)dd << 16);
    for (int ic0 = 0; ic0 < 256; ic0 += 32) {
      __syncthreads();
      for (int cpy = 0; cpy < 2; ++cpy) {
        int row = wv * 32 + cpy * 16 + lrow;
        async16(wbase + (((size_t)(oc0 + row)) << 8) + ic0 + lic,
                As + (wv * 32 + cpy * 16) * 32);
        int vss = row + dv - 1;
        const unsigned short* g =
            (uok && (unsigned)vss < 128u)
                ? t2b + (((size_t)(us * 128 + vss)) << 8) + ic0 + lic
                : zp + lic;
        async16(g, Bs + (wv * 32 + cpy * 16) * 32);
      }
      __syncthreads();
      abf8 a0 = *(const abf8*)(As + (wv * 32 + cl) * 32 + q * 8);
      abf8 a1 = *(const abf8*)(As + (wv * 32 + 16 + cl) * 32 + q * 8);
      for (int nt = 0; nt < 8; ++nt) {
        abf8 bf = *(const abf8*)(Bs + (nt * 16 + cl) * 32 + q * 8);
        acc[0][nt] = __builtin_amdgcn_mfma_f32_16x16x32_bf16(a0, bf, acc[0][nt], 0, 0, 0);
        acc[1][nt] = __builtin_amdgcn_mfma_f32_16x16x32_bf16(a1, bf, acc[1][nt], 0, 0, 0);
      }
    }
  }
  __syncthreads();
  for (int mt = 0; mt < 2; ++mt) {
    int ocr = wv * 32 + mt * 16 + q * 4;
    for (int r = 0; r < 4; ++r) {
      float bias = cv_bias[oc0 + ocr + r];
      for (int nt = 0; nt < 8; ++nt) {
        float xv = acc[mt][nt][r] + bias;
        float u_ = 0.7978845608028654f * xv * (1.0f + 0.044715f * xv * xv);
        float e = __expf(-2.0f * fabsf(u_));
        float th = (1.0f - e) / (1.0f + e);
        th = (u_ >= 0.0f) ? th : -th;
        float g = 0.5f * xv * (1.0f + th);
        Ost[(ocr + r) * 136 + nt * 16 + cl] = f2bf(g);
      }
    }
  }
  __syncthreads();
  const int rr = t >> 1, hf = t & 1;
  const uint4* src = (const uint4*)(Ost + rr * 136 + hf * 64);
  uint4* dst = (uint4*)(t3 + ((size_t)(b * 256 + oc0 + rr) << 14) + (u << 7) + hf * 64);
  for (int j = 0; j < 8; ++j) dst[j] = src[j];
}

// ---------------- K4: inverse transpose + IDWT -> out fp32 -------------------
__global__ __launch_bounds__(256) void k4_idwt(const unsigned short* __restrict__ t3,
                                               float* __restrict__ out) {
  __shared__ __align__(16) unsigned short L[4 * 32 * 34];  // [k][w2 32][h2 32+pad]
  const int t = threadIdx.x;
  const int w20 = (blockIdx.x & 3) * 32;
  const int h20 = (blockIdx.x >> 2) * 32;
  const int c = blockIdx.y, b = blockIdx.z;
  const unsigned short* t3b = t3 + (((size_t)(b * 256 + c * 4)) << 14);
  {
    const int row = t >> 1, hf = t & 1;
    const int k = row >> 5, w2i = row & 31;
    const unsigned* g = (const unsigned*)(t3b + ((size_t)k << 14) + ((w20 + w2i) << 7) + h20 + hf * 16);
    unsigned* l = (unsigned*)(L + (k * 32 + w2i) * 34 + hf * 16);
    for (int j = 0; j < 8; ++j) l[j] = g[j];
  }
  __syncthreads();
  const int w2 = t & 31;
  const int h2b = t >> 5;
  float* ob = out + (((size_t)(b * 64 + c)) << 16);
  for (int pass = 0; pass < 4; ++pass) {
    int h2 = h2b + pass * 8;
    int off = w2 * 34 + h2;
    float ll = bf2f(L[off]);
    float ch = bf2f(L[off + 1088]);
    float cv = bf2f(L[off + 2176]);
    float cd = bf2f(L[off + 3264]);
    float A  = (ll + ch + cv + cd) * 0.5f;
    float Bv = (ll + ch - cv - cd) * 0.5f;
    float Cv = (ll - ch + cv - cd) * 0.5f;
    float D  = (ll - ch - cv + cd) * 0.5f;
    int hg = (h20 + h2) * 2, wg = (w20 + w2) * 2;
    *(float2*)(ob + (size_t)hg * 256 + wg)       = make_float2(A, Bv);
    *(float2*)(ob + (size_t)(hg + 1) * 256 + wg) = make_float2(Cv, D);
  }
}

extern "C" void kernel_launch(void* const* d_in, const int* in_sizes, int n_in,
                              void* d_out, int out_size, void* d_ws, size_t ws_size,
                              hipStream_t stream) {
  const float* x    = (const float*)d_in[0];
  const float* dw_w = (const float*)d_in[1];
  const float* dw_b = (const float*)d_in[2];
  const float* pw_w = (const float*)d_in[3];
  const float* pw_b = (const float*)d_in[4];
  const float* cv_w = (const float*)d_in[5];
  const float* cv_b = (const float*)d_in[6];
  char* ws = (char*)d_ws;
  // ws layout: [0,4K) zero page | pwb 128K | cvb 1.18M | bufA @2MiB (t0,then t2)
  //            | bufB @70MiB (t1, then t3). Total ~134 MiB.
  unsigned short* pwb  = (unsigned short*)(ws + 4096);
  unsigned short* cvb  = (unsigned short*)(ws + 4096 + 131072);
  unsigned short* bufA = (unsigned short*)(ws + (size_t)(2u << 20));
  unsigned short* bufB = (unsigned short*)(ws + (size_t)(70u << 20));
  hipMemsetAsync(ws, 0, 4096, stream);  // zero page for K3 OOB lanes
  k0_prep<<<2304, 256, 0, stream>>>(pw_w, cv_w, pwb, cvb);
  k1a_dwt<<<dim3(16, 64, 8), 256, 0, stream>>>(x, bufA);
  k1b_dw<<<dim3(128, 8, 8), 256, 0, stream>>>(bufA, dw_w, dw_b, bufB);
  k2_pw<<<dim3(128, 2, 8), 256, 0, stream>>>(bufB, pwb, pw_b, bufA);
  k3_cv<<<dim3(2, 128, 8), 256, 0, stream>>>(bufA, cvb, cv_b, (const unsigned short*)ws, bufB);
  k4_idwt<<<dim3(16, 64, 8), 256, 0, stream>>>(bufB, (float*)d_out);
}

// Round 2
// 565.073 us; speedup vs baseline: 1.0672x; 1.0672x over previous
//
#include <hip/hip_runtime.h>
#include <hip/hip_bf16.h>

#define DEVI __device__ __forceinline__

typedef __attribute__((ext_vector_type(8))) short abf8;   // 8 x bf16 (4 VGPR)
typedef __attribute__((ext_vector_type(4))) float f32x4;  // MFMA acc

DEVI unsigned short f2bf(float f) {
  union { __hip_bfloat16 h; unsigned short u; } cvt;
  cvt.h = __float2bfloat16(f);
  return cvt.u;
}
DEVI float bf2f(unsigned short u) {
  return __uint_as_float(((unsigned)u) << 16);
}
DEVI void async16(const void* g, void* l) {
  // async global->LDS, 16B per lane; LDS dest = wave-uniform base + lane*16
  __builtin_amdgcn_global_load_lds((__attribute__((address_space(1))) void*)(g),
                                   (__attribute__((address_space(3))) void*)(l), 16, 0, 0);
}

// ---------------- K0: weight prep (bf16 casts + cv_w reorder) ----------------
__global__ __launch_bounds__(256) void k0_prep(const float* __restrict__ pw_w,
                                               const float* __restrict__ cv_w,
                                               unsigned short* __restrict__ pwb,
                                               unsigned short* __restrict__ cvb) {
  int id = blockIdx.x * 256 + threadIdx.x;
  if (id < 65536) pwb[id] = f2bf(pw_w[id]);
  if (id < 589824) {
    int dd = id >> 16;          // dy*3+dx
    int rem = id & 65535;       // oc*256+ic
    cvb[id] = f2bf(cv_w[(size_t)rem * 9 + dd]);
  }
}

// ---------------- K1a: Haar DWT + transpose -> t0[b][4c+k][u][v] bf16 --------
__global__ __launch_bounds__(256) void k1a_dwt(const float* __restrict__ x,
                                               unsigned short* __restrict__ t0) {
  __shared__ __align__(16) float L[64 * 65];
  const int t = threadIdx.x;
  const int u0 = (blockIdx.x & 3) * 32;
  const int v0 = (blockIdx.x >> 2) * 32;
  const int c = blockIdx.y, b = blockIdx.z;
  const float* xp = x + (((size_t)(b * 64 + c)) << 16);
  {
    const int row = t >> 2;
    const float* xr = xp + (size_t)(2 * v0 + row) * 256 + 2 * u0;
    float* Lr = L + row * 65;
    for (int j = 0; j < 4; ++j) {
      int col = ((t & 3) + j * 4) * 4;
      float4 val = *(const float4*)(xr + col);
      Lr[col] = val.x; Lr[col + 1] = val.y; Lr[col + 2] = val.z; Lr[col + 3] = val.w;
    }
  }
  __syncthreads();
  const int vv = t & 31;
  const int us = t >> 5;
  const size_t outc = ((size_t)(b * 256 + c * 4)) << 14;
  for (int pass = 0; pass < 4; ++pass) {
    int uu = us * 4 + pass;
    const float* Lp = L + (2 * vv) * 65 + 2 * uu;
    float a = Lp[0], bb = Lp[1], cc = Lp[65], dd = Lp[66];
    float sll = (a + bb + cc + dd) * 0.5f;
    float sch = (a + bb - cc - dd) * 0.5f;
    float scv = (a - bb + cc - dd) * 0.5f;
    float scd = (a - bb - cc + dd) * 0.5f;
    size_t base = outc + ((u0 + uu) << 7) + (v0 + vv);
    t0[base]         = f2bf(sll);
    t0[base + 16384] = f2bf(sch);
    t0[base + 32768] = f2bf(scv);
    t0[base + 49152] = f2bf(scd);
  }
}

// ---------------- K1b: depthwise 3x3 + bias -> t1 NHWC bf16 [b][u*128+v][ic] -
__global__ __launch_bounds__(256) void k1b_dw(const unsigned short* __restrict__ t0,
                                              const float* __restrict__ dww,
                                              const float* __restrict__ dwb,
                                              unsigned short* __restrict__ t1) {
  __shared__ __align__(16) unsigned short S[32 * 181];
  __shared__ __align__(16) unsigned short O[128 * 32];
  const int t = threadIdx.x;
  const int u0 = (blockIdx.x >> 3) * 8;
  const int v0 = (blockIdx.x & 7) * 16;
  const int icB = blockIdx.y * 32;
  const int b = blockIdx.z;
  const unsigned short* t0b = t0 + (((size_t)(b * 256 + icB)) << 14);
  for (int idx = t; idx < 5760; idx += 256) {
    int ic = idx / 180;
    int r = idx - ic * 180;
    int uu = r / 18;
    int vvq = r - uu * 18;
    int gu = u0 + uu - 1, gv = v0 + vvq - 1;
    unsigned short val = 0;
    if ((unsigned)gu < 128u && (unsigned)gv < 128u)
      val = t0b[((size_t)ic << 14) + (gu << 7) + gv];
    S[ic * 181 + r] = val;
  }
  __syncthreads();
  const int icp = t & 15, uu = (t >> 4) & 7, vh = t >> 7;
  const int cc0 = icB + icp * 2;
  float w0[9], w1[9];
  const float* wp = dww + cc0 * 9;
  for (int i = 0; i < 9; ++i) { w0[i] = wp[i]; w1[i] = wp[9 + i]; }
  const float b0 = dwb[cc0], b1 = dwb[cc0 + 1];
  const unsigned short* S0 = S + (icp * 2) * 181 + uu * 18 + vh * 8;
  const unsigned short* S1 = S0 + 181;
  float a0[3][3], a1[3][3];
  for (int du = 0; du < 3; ++du)
    for (int dv = 0; dv < 2; ++dv) {
      a0[du][dv] = bf2f(S0[du * 18 + dv]);
      a1[du][dv] = bf2f(S1[du * 18 + dv]);
    }
  unsigned* O32 = (unsigned*)O;
  for (int vv = 0; vv < 8; ++vv) {
    for (int du = 0; du < 3; ++du) {
      a0[du][2] = bf2f(S0[du * 18 + vv + 2]);
      a1[du][2] = bf2f(S1[du * 18 + vv + 2]);
    }
    float s0 = b0, s1 = b1;
    for (int du = 0; du < 3; ++du)
      for (int dv = 0; dv < 3; ++dv) {
        s0 += w0[du * 3 + dv] * a0[du][dv];
        s1 += w1[du * 3 + dv] * a1[du][dv];
      }
    int p = uu * 16 + vh * 8 + vv;
    O32[p * 16 + icp] = (unsigned)f2bf(s0) | ((unsigned)f2bf(s1) << 16);
    for (int du = 0; du < 3; ++du) {
      a0[du][0] = a0[du][1]; a0[du][1] = a0[du][2];
      a1[du][0] = a1[du][1]; a1[du][1] = a1[du][2];
    }
  }
  __syncthreads();
  const int p = t >> 1, hf = t & 1;
  const int pu = p >> 4, pv = p & 15;
  size_t gp = (size_t)((u0 + pu) * 128 + (v0 + pv));
  const uint4* src = (const uint4*)(O + p * 32 + hf * 16);
  uint4* dst = (uint4*)(t1 + ((((size_t)b * 16384) + gp) << 8) + icB + hf * 16);
  dst[0] = src[0];
  dst[1] = src[1];
}

// ---------------- K2: pointwise GEMM (M=128oc x N=128p, K=256) + bias --------
// Swizzled LDS tiles: slot(seg,row) = (seg + (row>>1))&3 -> conflict-free b128.
__global__ __launch_bounds__(256) void k2_pw(const unsigned short* __restrict__ t1,
                                             const unsigned short* __restrict__ pwb,
                                             const float* __restrict__ pw_bias,
                                             unsigned short* __restrict__ t2) {
  __shared__ __align__(16) char smem[34816];
  unsigned short* As = (unsigned short*)smem;            // [128 oc][32 ic] swizzled
  unsigned short* Bs = (unsigned short*)(smem + 8192);   // [128 p][32 ic] swizzled
  unsigned short* Ost = (unsigned short*)smem;           // [128 p][136] (union)
  const int t = threadIdx.x;
  const int wv = t >> 6, ln = t & 63;
  const int p0 = blockIdx.x * 128;
  const int oc0 = blockIdx.y * 128;
  const int b = blockIdx.z;
  const unsigned short* t1b = t1 + ((size_t)b << 22);
  const int q = ln >> 4, cl = ln & 15;
  const int lr = ln >> 2, sp = ln & 3;
  const int sc = (sp - (lr >> 1)) & 3;                 // staged seg content
  const int soff = ((q + (cl >> 1)) & 3) * 8;          // read slot offset
  f32x4 acc[2][8] = {};
  for (int ic0 = 0; ic0 < 256; ic0 += 32) {
    __syncthreads();
    for (int cpy = 0; cpy < 2; ++cpy) {
      int rb = wv * 32 + cpy * 16;
      async16(pwb + (((size_t)(oc0 + rb + lr)) << 8) + ic0 + sc * 8, As + rb * 32);
      async16(t1b + (((size_t)(p0 + rb + lr)) << 8) + ic0 + sc * 8, Bs + rb * 32);
    }
    __syncthreads();
    abf8 a0 = *(const abf8*)(As + (wv * 32 + cl) * 32 + soff);
    abf8 a1 = *(const abf8*)(As + (wv * 32 + 16 + cl) * 32 + soff);
    for (int nt = 0; nt < 8; ++nt) {
      abf8 bf = *(const abf8*)(Bs + (nt * 16 + cl) * 32 + soff);
      acc[0][nt] = __builtin_amdgcn_mfma_f32_16x16x32_bf16(a0, bf, acc[0][nt], 0, 0, 0);
      acc[1][nt] = __builtin_amdgcn_mfma_f32_16x16x32_bf16(a1, bf, acc[1][nt], 0, 0, 0);
    }
  }
  __syncthreads();
  for (int mt = 0; mt < 2; ++mt) {
    int ocr = wv * 32 + mt * 16 + q * 4;
    float bb0 = pw_bias[oc0 + ocr],     bb1 = pw_bias[oc0 + ocr + 1];
    float bb2 = pw_bias[oc0 + ocr + 2], bb3 = pw_bias[oc0 + ocr + 3];
    for (int nt = 0; nt < 8; ++nt) {
      int p = nt * 16 + cl;
      short4 pk;
      pk.x = (short)f2bf(acc[mt][nt][0] + bb0);
      pk.y = (short)f2bf(acc[mt][nt][1] + bb1);
      pk.z = (short)f2bf(acc[mt][nt][2] + bb2);
      pk.w = (short)f2bf(acc[mt][nt][3] + bb3);
      *(short4*)(Ost + p * 136 + ocr) = pk;
    }
  }
  __syncthreads();
  const int pr = t >> 1, hf = t & 1;
  const uint4* src = (const uint4*)(Ost + pr * 136 + hf * 64);
  uint4* dst = (uint4*)(t2 + (((size_t)(b * 16384 + p0 + pr)) << 8) + oc0 + hf * 64);
  for (int j = 0; j < 8; ++j) dst[j] = src[j];
}

// ---------------- K3: 3x3 conv, du-grouped implicit GEMM + bias + GELU -------
// Per (du, ic0) round: stage 1 input u-row [130 v][32 ic] (rows 0/129 stay
// zero = v-halo) + 3 dv weight tiles; 48 MFMA per barrier pair (was 16).
// Swizzle: slot(seg,R) = (seg + (R>>1))&3 -> conflict-free b128 reads.
__global__ __launch_bounds__(256) void k3_cv(const unsigned short* __restrict__ t2,
                                             const unsigned short* __restrict__ cvb,
                                             const float* __restrict__ cv_bias,
                                             unsigned short* __restrict__ t3) {
  __shared__ __align__(16) char smem[34816];
  unsigned short* As = (unsigned short*)smem;             // 3 dv x [128 oc][32 ic] = 24576 B
  unsigned short* Bs = (unsigned short*)(smem + 24576);   // [130 v][32 ic] = 8320 B
  unsigned short* Ost = (unsigned short*)smem;            // [128 oc][136] (union)
  const int t = threadIdx.x;
  const int wv = t >> 6, ln = t & 63;
  const int oc0 = blockIdx.x * 128;
  const int u = blockIdx.y;
  const int b = blockIdx.z;
  const unsigned short* t2b = t2 + ((size_t)b << 22);
  const int q = ln >> 4, cl = ln & 15;
  const int lr = ln >> 2, sp = ln & 3;
  const int scA = (sp - (lr >> 1)) & 3;          // A: swizzle by row-in-chunk
  const int scB = (sp - ((1 + lr) >> 1)) & 3;    // B: physical row = 1+ch*16+lr
  const int soffA = ((q + (cl >> 1)) & 3) * 8;
  // zero halo rows 0 and 129 of Bs (never overwritten by staging)
  if (t < 32) ((unsigned*)Bs)[t < 16 ? t : (2064 + (t - 16))] = 0;
  f32x4 acc[2][8] = {};
  for (int du = 0; du < 3; ++du) {
    const int us = u + du - 1;
    if ((unsigned)us >= 128u) continue;          // uniform per block
    const unsigned short* trow = t2b + ((size_t)us << 15);
    const unsigned short* wdu = cvb + (((size_t)(du * 3)) << 16);
    for (int ic0 = 0; ic0 < 256; ic0 += 32) {
      __syncthreads();
      for (int g = wv; g < 32; g += 4) {
        if (g < 24) {                             // A: 3 dv x 8 chunks
          int dv = g >> 3, ch = g & 7;
          async16(wdu + (((size_t)dv) << 16) + (((size_t)(oc0 + ch * 16 + lr)) << 8) + ic0 + scA * 8,
                  As + dv * 4096 + ch * 512);
        } else {                                  // B: 8 chunks, phys rows 1..128
          int ch = g - 24;
          async16(trow + (((size_t)(ch * 16 + lr)) << 8) + ic0 + scB * 8,
                  Bs + 32 + ch * 512);
        }
      }
      __syncthreads();
      for (int dv = 0; dv < 3; ++dv) {
        const unsigned short* Adv = As + dv * 4096;
        abf8 a0 = *(const abf8*)(Adv + (wv * 32 + cl) * 32 + soffA);
        abf8 a1 = *(const abf8*)(Adv + (wv * 32 + 16 + cl) * 32 + soffA);
        const int slotB = ((q + ((cl + dv) >> 1)) & 3) * 8;
        const unsigned short* Bbase = Bs + (cl + dv) * 32 + slotB;
        for (int nt = 0; nt < 8; ++nt) {
          abf8 bf = *(const abf8*)(Bbase + nt * 512);
          acc[0][nt] = __builtin_amdgcn_mfma_f32_16x16x32_bf16(a0, bf, acc[0][nt], 0, 0, 0);
          acc[1][nt] = __builtin_amdgcn_mfma_f32_16x16x32_bf16(a1, bf, acc[1][nt], 0, 0, 0);
        }
      }
    }
  }
  __syncthreads();
  for (int mt = 0; mt < 2; ++mt) {
    int ocr = wv * 32 + mt * 16 + q * 4;
    for (int r = 0; r < 4; ++r) {
      float bias = cv_bias[oc0 + ocr + r];
      for (int nt = 0; nt < 8; ++nt) {
        float xv = acc[mt][nt][r] + bias;
        float u_ = 0.7978845608028654f * xv * (1.0f + 0.044715f * xv * xv);
        float e = __expf(-2.0f * fabsf(u_));
        float th = (1.0f - e) / (1.0f + e);
        th = (u_ >= 0.0f) ? th : -th;
        float g = 0.5f * xv * (1.0f + th);
        Ost[(ocr + r) * 136 + nt * 16 + cl] = f2bf(g);
      }
    }
  }
  __syncthreads();
  const int rr = t >> 1, hf = t & 1;
  const uint4* src = (const uint4*)(Ost + rr * 136 + hf * 64);
  uint4* dst = (uint4*)(t3 + ((size_t)(b * 256 + oc0 + rr) << 14) + (u << 7) + hf * 64);
  for (int j = 0; j < 8; ++j) dst[j] = src[j];
}

// ---------------- K4: inverse transpose + IDWT -> out fp32 -------------------
__global__ __launch_bounds__(256) void k4_idwt(const unsigned short* __restrict__ t3,
                                               float* __restrict__ out) {
  __shared__ __align__(16) unsigned short L[4 * 32 * 34];
  const int t = threadIdx.x;
  const int w20 = (blockIdx.x & 3) * 32;
  const int h20 = (blockIdx.x >> 2) * 32;
  const int c = blockIdx.y, b = blockIdx.z;
  const unsigned short* t3b = t3 + (((size_t)(b * 256 + c * 4)) << 14);
  {
    const int row = t >> 1, hf = t & 1;
    const int k = row >> 5, w2i = row & 31;
    const unsigned* g = (const unsigned*)(t3b + ((size_t)k << 14) + ((w20 + w2i) << 7) + h20 + hf * 16);
    unsigned* l = (unsigned*)(L + (k * 32 + w2i) * 34 + hf * 16);
    for (int j = 0; j < 8; ++j) l[j] = g[j];
  }
  __syncthreads();
  const int w2 = t & 31;
  const int h2b = t >> 5;
  float* ob = out + (((size_t)(b * 64 + c)) << 16);
  for (int pass = 0; pass < 4; ++pass) {
    int h2 = h2b + pass * 8;
    int off = w2 * 34 + h2;
    float ll = bf2f(L[off]);
    float ch = bf2f(L[off + 1088]);
    float cv = bf2f(L[off + 2176]);
    float cd = bf2f(L[off + 3264]);
    float A  = (ll + ch + cv + cd) * 0.5f;
    float Bv = (ll + ch - cv - cd) * 0.5f;
    float Cv = (ll - ch + cv - cd) * 0.5f;
    float D  = (ll - ch - cv + cd) * 0.5f;
    int hg = (h20 + h2) * 2, wg = (w20 + w2) * 2;
    *(float2*)(ob + (size_t)hg * 256 + wg)       = make_float2(A, Bv);
    *(float2*)(ob + (size_t)(hg + 1) * 256 + wg) = make_float2(Cv, D);
  }
}

extern "C" void kernel_launch(void* const* d_in, const int* in_sizes, int n_in,
                              void* d_out, int out_size, void* d_ws, size_t ws_size,
                              hipStream_t stream) {
  const float* x    = (const float*)d_in[0];
  const float* dw_w = (const float*)d_in[1];
  const float* dw_b = (const float*)d_in[2];
  const float* pw_w = (const float*)d_in[3];
  const float* pw_b = (const float*)d_in[4];
  const float* cv_w = (const float*)d_in[5];
  const float* cv_b = (const float*)d_in[6];
  char* ws = (char*)d_ws;
  // ws layout: pwb @4K (128K) | cvb (1.18M) | bufA @2MiB (t0, then t2)
  //            | bufB @70MiB (t1, then t3). Total ~134 MiB.
  unsigned short* pwb  = (unsigned short*)(ws + 4096);
  unsigned short* cvb  = (unsigned short*)(ws + 4096 + 131072);
  unsigned short* bufA = (unsigned short*)(ws + (size_t)(2u << 20));
  unsigned short* bufB = (unsigned short*)(ws + (size_t)(70u << 20));
  k0_prep<<<2304, 256, 0, stream>>>(pw_w, cv_w, pwb, cvb);
  k1a_dwt<<<dim3(16, 64, 8), 256, 0, stream>>>(x, bufA);
  k1b_dw<<<dim3(128, 8, 8), 256, 0, stream>>>(bufA, dw_w, dw_b, bufB);
  k2_pw<<<dim3(128, 2, 8), 256, 0, stream>>>(bufB, pwb, pw_b, bufA);
  k3_cv<<<dim3(2, 128, 8), 256, 0, stream>>>(bufA, cvb, cv_b, bufB);
  k4_idwt<<<dim3(16, 64, 8), 256, 0, stream>>>(bufB, (float*)d_out);
}